// Round 15
// baseline (33.917 us; speedup 1.0000x reference)
//
#include <hip/hip_runtime.h>
#include <hip/hip_fp16.h>

#define HW_  (1024 * 1024)   // 2^20
#define R_   8               // output rows per block
#define RS_  (R_ + 4)        // staged rows [r0-2, r0+9]
#define CW_  512             // output cols per block
#define SW_  528             // staged cols [c0-4, c0+524), mult of 16 (bank-neutral di)
#define SOFF (RS_ * SW_)     // 6336 half2: strip starts here
#define NB_  512             // threads per block
#define NG   (SOFF / 4)      // 1584 float4 staging groups

// ABLATION ROUND: body executed TWICE (second pi0 made opaque via asm so no
// CSE); acc = 0.5*(a1+a2) is bitwise-identical to one pass. dur delta = body time.
template<int ODD>
__device__ __forceinline__ float ploss_body(
        const __half2* st, const float* __restrict__ img, const float* __restrict__ lg,
        int r0, int col0, int colk, unsigned pi) {
    const float  T  = 0.21072103131565256f;  // -2*ln(0.9)
    const __half Th = __float2half(0.21072103f);
    const uint2*    st64 = reinterpret_cast<const uint2*>(st);
    const unsigned* st32 = reinterpret_cast<const unsigned*>(st);
    float acc = 0.0f, pp = 1.0f;

    #pragma unroll
    for (int kk = 0; kk < R_; ++kk) {
        int rowk = kk;
        int i  = (int)((pi * 171u) >> 9);      // pi/3
        int j  = (int)pi - 3 * i;
        int di = 2 * i - 2, dj = 2 * j - 2;
        float p;
        if (col0 < 1016) {
            // ---- fast path: 4 b64 + 1 b32 LDS reads, parity-free extraction ----
            int b0 = ((rowk + 2 + di) * SW_ + (colk + 4 + dj)) >> 1;  // parity==ODD
            unsigned h0, h1, h2, h3, h5, h6, h7, h8;
            if constexpr (!ODD) {
                uint2 va = st64[b0 + 0], vb = st64[b0 + 1],
                      vc = st64[b0 + 2], vd = st64[b0 + 3];
                unsigned w8 = st32[2 * b0 + 8];
                h0 = va.x; h1 = va.y; h2 = vb.x; h3 = vb.y;
                h5 = vc.y; h6 = vd.x; h7 = vd.y; h8 = w8;
            } else {
                unsigned w0 = st32[2 * b0 + 1];
                uint2 va = st64[b0 + 1], vb = st64[b0 + 2],
                      vc = st64[b0 + 3], vd = st64[b0 + 4];
                h0 = w0;   h1 = va.x; h2 = va.y; h3 = vb.x;
                h5 = vc.x; h6 = vc.y; h7 = vd.x; h8 = vd.y;
            }
            __half2 N = *reinterpret_cast<__half2*>(&h5);
            __half  nh = __low2half(N);
            float   ns = __half2float(__high2half(N));
            float c2 = 1.0f - ns, c1 = ns - c2;
            #define EDGE_(hw) ({ __half2 _t = *reinterpret_cast<__half2*>(&(hw)); \
                (__hle(__habs(__hsub(__low2half(_t), nh)), Th)) \
                    ? fmaf(__half2float(__high2half(_t)), c1, c2) : 1.0f; })
            float f0 = EDGE_(h0);
            float f1 = EDGE_(h1);
            float f2 = EDGE_(h2);
            float f3 = EDGE_(h3);
            float f4 = fmaf(ns, c1, c2);       // self-edge q=5, |d|=0
            float f5 = EDGE_(h6);
            float f6 = EDGE_(h7);
            float f7 = EDGE_(h8);
            #undef EDGE_
            p = ((f0 * f1) * (f2 * f3)) * ((f4 * f5) * (f6 * f7));
        } else if (r0 + rowk < 1023) {
            // ---- row-wrap path: taps q>=qs from the LDS strip ----
            int a0 = (rowk + 2 + di) * SW_ + (colk + 4 + dj);
            int qs = 1024 - col0;                               // 1..8
            int sbase = SOFF + (rowk + 2 + di) * 12 + (col0 - 1022 + dj);
            #define RDW_(q) __half22float2(st[(((q) < qs) ? a0 : sbase) + (q)])
            float2 t0 = RDW_(0);
            float2 t1 = RDW_(1);
            float2 t2 = RDW_(2);
            float2 t3 = RDW_(3);
            float2 t5 = RDW_(5);
            float2 t6 = RDW_(6);
            float2 t7 = RDW_(7);
            float2 t8 = RDW_(8);
            #undef RDW_
            float nimg = t5.x;
            float c1 = 2.0f * t5.y - 1.0f, c2 = 1.0f - t5.y;
            float f0 = (fabsf(nimg - t0.x) <= T) ? fmaf(t0.y, c1, c2) : 1.0f;
            float f1 = (fabsf(nimg - t1.x) <= T) ? fmaf(t1.y, c1, c2) : 1.0f;
            float f2 = (fabsf(nimg - t2.x) <= T) ? fmaf(t2.y, c1, c2) : 1.0f;
            float f3 = (fabsf(nimg - t3.x) <= T) ? fmaf(t3.y, c1, c2) : 1.0f;
            float f4 = fmaf(t5.y, c1, c2);
            float f5 = (fabsf(nimg - t6.x) <= T) ? fmaf(t6.y, c1, c2) : 1.0f;
            float f6 = (fabsf(nimg - t7.x) <= T) ? fmaf(t7.y, c1, c2) : 1.0f;
            float f7 = (fabsf(nimg - t8.x) <= T) ? fmaf(t8.y, c1, c2) : 1.0f;
            p = ((f0 * f1) * (f2 * f3)) * ((f4 * f5) * (f6 * f7));
        } else {
            // ---- pi-crossing sites (si0 >= 2^20-8): exact global path ----
            int m0 = (int)pi * HW_ + ((r0 + rowk) << 10) + col0;   // = 9l
            float nimg = 0.0f, nm = 0.0f;
            {
                int m = m0 + 5;
                int piq = m >> 20, siq = m & (HW_ - 1);
                int iq = (piq * 171) >> 9, jq = piq - 3 * iq;
                int rq = (siq >> 10) + 2 * iq - 2;
                int cq = (siq & 1023) + 2 * jq - 2;
                if ((unsigned)rq < 1024u && (unsigned)cq < 1024u) {
                    int off = (rq << 10) | cq;
                    nimg = img[off];
                    nm = 1.0f / (1.0f + __expf(-lg[off]));
                }
            }
            float c1 = 2.0f * nm - 1.0f, c2 = 1.0f - nm;
            p = 1.0f;
            #pragma unroll
            for (int q = 0; q < 9; ++q) {
                if (q == 4) continue;
                int m = m0 + q;
                int piq = m >> 20, siq = m & (HW_ - 1);
                int iq = (piq * 171) >> 9, jq = piq - 3 * iq;
                int rq = (siq >> 10) + 2 * iq - 2;
                int cq = (siq & 1023) + 2 * jq - 2;
                float eimg = 0.0f, em = 0.0f;
                if ((unsigned)rq < 1024u && (unsigned)cq < 1024u) {
                    int off = (rq << 10) | cq;
                    eimg = img[off];
                    em = 1.0f / (1.0f + __expf(-lg[off]));
                }
                p *= (fabsf(nimg - eimg) <= T) ? fmaf(em, c1, c2) : 1.0f;
            }
        }
        if (kk & 1) acc -= __log2f(pp * p);    // one log per row-pair (16 factors)
        else        pp = p;
        pi += 5u;                              // +2*1024 mod 9
        if (pi >= 9u) pi -= 9u;
    }
    return acc;
}

__global__ __launch_bounds__(NB_) void ploss15(
        const float* __restrict__ logits_,
        const float* __restrict__ image_,
        float* __restrict__ part, int nwg, float scale) {
    __shared__ __half2 st[SOFF + 144];   // 25.9 KB

    // bijective XCD-chunked swizzle (nwg % 8 == 0)
    int bid = blockIdx.x;
    int wg  = (bid & 7) * (nwg >> 3) + (bid >> 3);

    int c   = wg >> 8;                 // 256 blocks per class
    int rem = wg & 255;
    int r0  = (rem >> 1) * R_;
    int c0  = (rem & 1) * CW_;
    const float* __restrict__ img = image_  + (size_t)c * HW_;
    const float* __restrict__ lg  = logits_ + (size_t)c * HW_;
    int tid = threadIdx.x;

    // ---- stage main tile: float4 groups, no partial vectors by construction ----
    for (unsigned g = tid; g < NG; g += NB_) {
        unsigned rr = g / 132u;            // 132 groups per row
        int gc  = (int)(g - rr * 132u);
        int row = r0 - 2 + (int)rr;
        int col4 = c0 - 4 + (gc << 2);
        float4 w;
        __half2* wh = reinterpret_cast<__half2*>(&w);
        if ((unsigned)row < 1024u && (unsigned)col4 < 1021u) {
            const float4 a = *reinterpret_cast<const float4*>(img + ((size_t)row << 10) + col4);
            const float4 b = *reinterpret_cast<const float4*>(lg  + ((size_t)row << 10) + col4);
            wh[0] = __floats2half2_rn(a.x, 1.0f / (1.0f + __expf(-b.x)));
            wh[1] = __floats2half2_rn(a.y, 1.0f / (1.0f + __expf(-b.y)));
            wh[2] = __floats2half2_rn(a.z, 1.0f / (1.0f + __expf(-b.z)));
            wh[3] = __floats2half2_rn(a.w, 1.0f / (1.0f + __expf(-b.w)));
        } else {
            w = make_float4(0.0f, 0.0f, 0.0f, 0.0f);
        }
        reinterpret_cast<float4*>(st)[g] = w;
    }
    // ---- strip (right tiles only): 12 rows [r0-1, r0+10], cols [-2, 10) ----
    if (c0 != 0 && tid < 144) {
        unsigned rr = (unsigned)tid / 12u;
        int cc = tid - (int)rr * 12;
        int row = r0 - 1 + (int)rr, col = cc - 2;
        float iv = 0.0f, mv = 0.0f;
        if ((unsigned)row < 1024u && (unsigned)col < 1024u) {
            int off = (row << 10) | col;
            iv = img[off];
            mv = 1.0f / (1.0f + __expf(-lg[off]));
        }
        st[SOFF + tid] = __floats2half2_rn(iv, mv);
    }
    __syncthreads();

    // thread->site remap: waves 0-3 even cols, waves 4-7 odd cols (uniform parity)
    int tsub  = tid & 255;
    int colk0 = (tsub << 1) | (tid >> 8);
    int col0  = c0 + colk0;                    // loop-invariant per thread
    unsigned pi0 = (2u * (unsigned)((r0 << 10) + col0)) % 9u;

    // ---- pass 1 ----
    float acc1;
    if (tid < 256) acc1 = ploss_body<0>(st, img, lg, r0, col0, colk0, pi0);
    else           acc1 = ploss_body<1>(st, img, lg, r0, col0, colk0, pi0);

    // ---- pass 2: pi0 made opaque -> full re-execution, bitwise-equal result ----
    unsigned pi0b = pi0;
    asm volatile("" : "+v"(pi0b));             // compiler can't prove pi0b == pi0
    float acc2;
    if (tid < 256) acc2 = ploss_body<0>(st, img, lg, r0, col0, colk0, pi0b);
    else           acc2 = ploss_body<1>(st, img, lg, r0, col0, colk0, pi0b);

    float acc = (acc1 + acc2) * 0.5f;          // == acc1 exactly (a+a)*0.5
    acc *= scale;                              // scale includes ln2

    // wave shuffle reduce -> LDS -> ONE plain store per block (no atomics)
    #pragma unroll
    for (int o = 32; o > 0; o >>= 1) acc += __shfl_down(acc, o, 64);
    __shared__ float sm[8];
    int lane = tid & 63, wid = tid >> 6;
    if (lane == 0) sm[wid] = acc;
    __syncthreads();
    if (tid == 0) {
        float s = 0.0f;
        #pragma unroll
        for (int w2 = 0; w2 < 8; ++w2) s += sm[w2];
        part[wg] = s;
    }
}

// single-block final reduce of nwg partials
__global__ __launch_bounds__(256) void preduce(
        const float* __restrict__ part, float* __restrict__ out, int n) {
    float acc = 0.0f;
    for (int i = threadIdx.x; i < n; i += 256) acc += part[i];
    #pragma unroll
    for (int o = 32; o > 0; o >>= 1) acc += __shfl_down(acc, o, 64);
    __shared__ float sm[4];
    int lane = threadIdx.x & 63, wid = threadIdx.x >> 6;
    if (lane == 0) sm[wid] = acc;
    __syncthreads();
    if (threadIdx.x == 0) out[0] = sm[0] + sm[1] + sm[2] + sm[3];
}

extern "C" void kernel_launch(void* const* d_in, const int* in_sizes, int n_in,
                              void* d_out, int out_size, void* d_ws, size_t ws_size,
                              hipStream_t stream) {
    const float* logits = (const float*)d_in[0];  // inputs (N,1,H,W) fp32
    const float* image  = (const float*)d_in[1];  // image  (N,1,H,W) fp32
    float* out  = (float*)d_out;
    float* part = (float*)d_ws;                   // nwg floats of scratch

    int nc  = in_sizes[0] / HW_;                          // 4
    int nwg = nc * (1024 / R_) * (1024 / CW_);            // 1024
    // acc is in log2 units -> fold ln2 into the scale
    float scale = 0.69314718055994531f / ((float)nc * (float)HW_);

    ploss15<<<nwg, NB_, 0, stream>>>(logits, image, part, nwg, scale);
    preduce<<<1, 256, 0, stream>>>(part, out, nwg);
}

// Round 16
// 26.951 us; speedup vs baseline: 1.2585x; 1.2585x over previous
//
#include <hip/hip_runtime.h>
#include <hip/hip_fp16.h>

#define HW_  (1024 * 1024)   // 2^20
#define R_   8               // output rows per block
#define RS_  (R_ + 4)        // staged rows [r0-2, r0+9]
#define CW_  512             // output cols per block
#define SW_  528             // staged cols [c0-4, c0+524), mult of 16 (bank-neutral di)
#define SOFF (RS_ * SW_)     // 6336 half2: strip starts here
#define NB_  512             // threads per block
#define NG   (SOFF / 4)      // 1584 float4 staging groups

// ABLATION ROUND 2: STAGING executed TWICE (second pass offset by asm-opaque
// zero -> full recompute; same values to same slots from same thread = no race,
// bitwise-identical LDS). dur delta = staging compute time. Body = R12 verbatim.
template<int ODD>
__device__ __forceinline__ float ploss_body(
        const __half2* st, const float* __restrict__ img, const float* __restrict__ lg,
        int r0, int col0, int colk, unsigned pi) {
    const float  T  = 0.21072103131565256f;  // -2*ln(0.9)
    const __half Th = __float2half(0.21072103f);
    const uint2*    st64 = reinterpret_cast<const uint2*>(st);
    const unsigned* st32 = reinterpret_cast<const unsigned*>(st);
    float acc = 0.0f, pp = 1.0f;

    #pragma unroll
    for (int kk = 0; kk < R_; ++kk) {
        int rowk = kk;
        int i  = (int)((pi * 171u) >> 9);      // pi/3
        int j  = (int)pi - 3 * i;
        int di = 2 * i - 2, dj = 2 * j - 2;
        float p;
        if (col0 < 1016) {
            // ---- fast path: 4 b64 + 1 b32 LDS reads, parity-free extraction ----
            int b0 = ((rowk + 2 + di) * SW_ + (colk + 4 + dj)) >> 1;  // parity==ODD
            unsigned h0, h1, h2, h3, h5, h6, h7, h8;
            if constexpr (!ODD) {
                uint2 va = st64[b0 + 0], vb = st64[b0 + 1],
                      vc = st64[b0 + 2], vd = st64[b0 + 3];
                unsigned w8 = st32[2 * b0 + 8];
                h0 = va.x; h1 = va.y; h2 = vb.x; h3 = vb.y;
                h5 = vc.y; h6 = vd.x; h7 = vd.y; h8 = w8;
            } else {
                unsigned w0 = st32[2 * b0 + 1];
                uint2 va = st64[b0 + 1], vb = st64[b0 + 2],
                      vc = st64[b0 + 3], vd = st64[b0 + 4];
                h0 = w0;   h1 = va.x; h2 = va.y; h3 = vb.x;
                h5 = vc.x; h6 = vc.y; h7 = vd.x; h8 = vd.y;
            }
            __half2 N = *reinterpret_cast<__half2*>(&h5);
            __half  nh = __low2half(N);
            float   ns = __half2float(__high2half(N));
            float c2 = 1.0f - ns, c1 = ns - c2;
            #define EDGE_(hw) ({ __half2 _t = *reinterpret_cast<__half2*>(&(hw)); \
                (__hle(__habs(__hsub(__low2half(_t), nh)), Th)) \
                    ? fmaf(__half2float(__high2half(_t)), c1, c2) : 1.0f; })
            float f0 = EDGE_(h0);
            float f1 = EDGE_(h1);
            float f2 = EDGE_(h2);
            float f3 = EDGE_(h3);
            float f4 = fmaf(ns, c1, c2);       // self-edge q=5, |d|=0
            float f5 = EDGE_(h6);
            float f6 = EDGE_(h7);
            float f7 = EDGE_(h8);
            #undef EDGE_
            p = ((f0 * f1) * (f2 * f3)) * ((f4 * f5) * (f6 * f7));
        } else if (r0 + rowk < 1023) {
            // ---- row-wrap path: taps q>=qs from the LDS strip ----
            int a0 = (rowk + 2 + di) * SW_ + (colk + 4 + dj);
            int qs = 1024 - col0;                               // 1..8
            int sbase = SOFF + (rowk + 2 + di) * 12 + (col0 - 1022 + dj);
            #define RDW_(q) __half22float2(st[(((q) < qs) ? a0 : sbase) + (q)])
            float2 t0 = RDW_(0);
            float2 t1 = RDW_(1);
            float2 t2 = RDW_(2);
            float2 t3 = RDW_(3);
            float2 t5 = RDW_(5);
            float2 t6 = RDW_(6);
            float2 t7 = RDW_(7);
            float2 t8 = RDW_(8);
            #undef RDW_
            float nimg = t5.x;
            float c1 = 2.0f * t5.y - 1.0f, c2 = 1.0f - t5.y;
            float f0 = (fabsf(nimg - t0.x) <= T) ? fmaf(t0.y, c1, c2) : 1.0f;
            float f1 = (fabsf(nimg - t1.x) <= T) ? fmaf(t1.y, c1, c2) : 1.0f;
            float f2 = (fabsf(nimg - t2.x) <= T) ? fmaf(t2.y, c1, c2) : 1.0f;
            float f3 = (fabsf(nimg - t3.x) <= T) ? fmaf(t3.y, c1, c2) : 1.0f;
            float f4 = fmaf(t5.y, c1, c2);
            float f5 = (fabsf(nimg - t6.x) <= T) ? fmaf(t6.y, c1, c2) : 1.0f;
            float f6 = (fabsf(nimg - t7.x) <= T) ? fmaf(t7.y, c1, c2) : 1.0f;
            float f7 = (fabsf(nimg - t8.x) <= T) ? fmaf(t8.y, c1, c2) : 1.0f;
            p = ((f0 * f1) * (f2 * f3)) * ((f4 * f5) * (f6 * f7));
        } else {
            // ---- pi-crossing sites (si0 >= 2^20-8): exact global path ----
            int m0 = (int)pi * HW_ + ((r0 + rowk) << 10) + col0;   // = 9l
            float nimg = 0.0f, nm = 0.0f;
            {
                int m = m0 + 5;
                int piq = m >> 20, siq = m & (HW_ - 1);
                int iq = (piq * 171) >> 9, jq = piq - 3 * iq;
                int rq = (siq >> 10) + 2 * iq - 2;
                int cq = (siq & 1023) + 2 * jq - 2;
                if ((unsigned)rq < 1024u && (unsigned)cq < 1024u) {
                    int off = (rq << 10) | cq;
                    nimg = img[off];
                    nm = 1.0f / (1.0f + __expf(-lg[off]));
                }
            }
            float c1 = 2.0f * nm - 1.0f, c2 = 1.0f - nm;
            p = 1.0f;
            #pragma unroll
            for (int q = 0; q < 9; ++q) {
                if (q == 4) continue;
                int m = m0 + q;
                int piq = m >> 20, siq = m & (HW_ - 1);
                int iq = (piq * 171) >> 9, jq = piq - 3 * iq;
                int rq = (siq >> 10) + 2 * iq - 2;
                int cq = (siq & 1023) + 2 * jq - 2;
                float eimg = 0.0f, em = 0.0f;
                if ((unsigned)rq < 1024u && (unsigned)cq < 1024u) {
                    int off = (rq << 10) | cq;
                    eimg = img[off];
                    em = 1.0f / (1.0f + __expf(-lg[off]));
                }
                p *= (fabsf(nimg - eimg) <= T) ? fmaf(em, c1, c2) : 1.0f;
            }
        }
        if (kk & 1) acc -= __log2f(pp * p);    // one log per row-pair (16 factors)
        else        pp = p;
        pi += 5u;                              // +2*1024 mod 9
        if (pi >= 9u) pi -= 9u;
    }
    return acc;
}

__global__ __launch_bounds__(NB_) void ploss16(
        const float* __restrict__ logits_,
        const float* __restrict__ image_,
        float* __restrict__ part, int nwg, float scale) {
    __shared__ __half2 st[SOFF + 144];   // 25.9 KB

    // bijective XCD-chunked swizzle (nwg % 8 == 0)
    int bid = blockIdx.x;
    int wg  = (bid & 7) * (nwg >> 3) + (bid >> 3);

    int c   = wg >> 8;                 // 256 blocks per class
    int rem = wg & 255;
    int r0  = (rem >> 1) * R_;
    int c0  = (rem & 1) * CW_;
    const float* __restrict__ img = image_  + (size_t)c * HW_;
    const float* __restrict__ lg  = logits_ + (size_t)c * HW_;
    int tid = threadIdx.x;

    // ---- STAGING x2 (ablation): pass 1 normal; pass 2 offset by opaque zero ----
    #pragma unroll 1
    for (int pass = 0; pass < 2; ++pass) {
        int zero = 0;
        if (pass == 1) asm volatile("" : "+v"(zero));   // opaque: forces recompute
        int r0z = r0 + zero;                            // == r0 at runtime
        for (unsigned g = tid; g < NG; g += NB_) {
            unsigned rr = g / 132u;            // 132 groups per row
            int gc  = (int)(g - rr * 132u);
            int row = r0z - 2 + (int)rr;
            int col4 = c0 - 4 + (gc << 2);
            float4 w;
            __half2* wh = reinterpret_cast<__half2*>(&w);
            if ((unsigned)row < 1024u && (unsigned)col4 < 1021u) {
                const float4 a = *reinterpret_cast<const float4*>(img + ((size_t)row << 10) + col4);
                const float4 b = *reinterpret_cast<const float4*>(lg  + ((size_t)row << 10) + col4);
                wh[0] = __floats2half2_rn(a.x, 1.0f / (1.0f + __expf(-b.x)));
                wh[1] = __floats2half2_rn(a.y, 1.0f / (1.0f + __expf(-b.y)));
                wh[2] = __floats2half2_rn(a.z, 1.0f / (1.0f + __expf(-b.z)));
                wh[3] = __floats2half2_rn(a.w, 1.0f / (1.0f + __expf(-b.w)));
            } else {
                w = make_float4(0.0f, 0.0f, 0.0f, 0.0f);
            }
            reinterpret_cast<float4*>(st)[g] = w;
        }
        // ---- strip (right tiles only): 12 rows [r0-1, r0+10], cols [-2, 10) ----
        if (c0 != 0 && tid < 144) {
            unsigned rr = (unsigned)tid / 12u;
            int cc = tid - (int)rr * 12;
            int row = r0z - 1 + (int)rr, col = cc - 2;
            float iv = 0.0f, mv = 0.0f;
            if ((unsigned)row < 1024u && (unsigned)col < 1024u) {
                int off = (row << 10) | col;
                iv = img[off];
                mv = 1.0f / (1.0f + __expf(-lg[off]));
            }
            st[SOFF + tid] = __floats2half2_rn(iv, mv);
        }
    }
    __syncthreads();

    // thread->site remap: waves 0-3 even cols, waves 4-7 odd cols (uniform parity)
    int tsub  = tid & 255;
    int colk0 = (tsub << 1) | (tid >> 8);
    int col0  = c0 + colk0;                    // loop-invariant per thread
    unsigned pi0 = (2u * (unsigned)((r0 << 10) + col0)) % 9u;

    float acc;
    if (tid < 256) acc = ploss_body<0>(st, img, lg, r0, col0, colk0, pi0);
    else           acc = ploss_body<1>(st, img, lg, r0, col0, colk0, pi0);
    acc *= scale;                              // scale includes ln2

    // wave shuffle reduce -> LDS -> ONE plain store per block (no atomics)
    #pragma unroll
    for (int o = 32; o > 0; o >>= 1) acc += __shfl_down(acc, o, 64);
    __shared__ float sm[8];
    int lane = tid & 63, wid = tid >> 6;
    if (lane == 0) sm[wid] = acc;
    __syncthreads();
    if (tid == 0) {
        float s = 0.0f;
        #pragma unroll
        for (int w2 = 0; w2 < 8; ++w2) s += sm[w2];
        part[wg] = s;
    }
}

// single-block final reduce of nwg partials
__global__ __launch_bounds__(256) void preduce(
        const float* __restrict__ part, float* __restrict__ out, int n) {
    float acc = 0.0f;
    for (int i = threadIdx.x; i < n; i += 256) acc += part[i];
    #pragma unroll
    for (int o = 32; o > 0; o >>= 1) acc += __shfl_down(acc, o, 64);
    __shared__ float sm[4];
    int lane = threadIdx.x & 63, wid = threadIdx.x >> 6;
    if (lane == 0) sm[wid] = acc;
    __syncthreads();
    if (threadIdx.x == 0) out[0] = sm[0] + sm[1] + sm[2] + sm[3];
}

extern "C" void kernel_launch(void* const* d_in, const int* in_sizes, int n_in,
                              void* d_out, int out_size, void* d_ws, size_t ws_size,
                              hipStream_t stream) {
    const float* logits = (const float*)d_in[0];  // inputs (N,1,H,W) fp32
    const float* image  = (const float*)d_in[1];  // image  (N,1,H,W) fp32
    float* out  = (float*)d_out;
    float* part = (float*)d_ws;                   // nwg floats of scratch

    int nc  = in_sizes[0] / HW_;                          // 4
    int nwg = nc * (1024 / R_) * (1024 / CW_);            // 1024
    // acc is in log2 units -> fold ln2 into the scale
    float scale = 0.69314718055994531f / ((float)nc * (float)HW_);

    ploss16<<<nwg, NB_, 0, stream>>>(logits, image, part, nwg, scale);
    preduce<<<1, 256, 0, stream>>>(part, out, nwg);
}

// Round 18
// 23.934 us; speedup vs baseline: 1.4171x; 1.1261x over previous
//
#include <hip/hip_runtime.h>
#include <hip/hip_fp16.h>

#define HW_  (1024 * 1024)   // 2^20
#define R_   8               // output rows per block
#define RS_  (R_ + 4)        // staged rows [r0-2, r0+9]
#define CW_  512             // output cols per block
#define SW_  528             // staged cols [c0-4, c0+524), mult of 16 (bank-neutral di)
#define SOFF (RS_ * SW_)     // 6336 half2: strip starts here
#define NB_  512             // threads per block
#define NGA  1188            // staged rows 0..8  (9 x 132 float4 groups)
#define NGB  396             // staged rows 9..11 (3 x 132 groups; <= NB_, one/thread)

// Split-tile pipeline: stage rows 0-8 + strip; ISSUE rows 9-11 loads to regs;
// barrier; body rows 0-3 (reads staged rows <=7); write rows 9-11 (sigmoid);
// barrier; body rows 4-7 (reads staged rows 4..11). B's HBM latency hides
// under body-A. NGB=396 <= 512 threads: full coverage, one group per thread.
template<int ODD, int K0>
__device__ __forceinline__ float ploss_half(
        const __half2* st, const float* __restrict__ img, const float* __restrict__ lg,
        int r0, int col0, int colk, unsigned pi) {
    const float  T  = 0.21072103131565256f;  // -2*ln(0.9)
    const __half Th = __float2half(0.21072103f);
    const uint2*    st64 = reinterpret_cast<const uint2*>(st);
    const unsigned* st32 = reinterpret_cast<const unsigned*>(st);
    float acc = 0.0f, pp = 1.0f;

    #pragma unroll
    for (int u = 0; u < 4; ++u) {
        int rowk = K0 + u;
        int i  = (int)((pi * 171u) >> 9);      // pi/3
        int j  = (int)pi - 3 * i;
        int di = 2 * i - 2, dj = 2 * j - 2;
        float p;
        if (col0 < 1016) {
            // ---- fast path: 4 b64 + 1 b32 LDS reads, parity-free extraction ----
            int b0 = ((rowk + 2 + di) * SW_ + (colk + 4 + dj)) >> 1;  // parity==ODD
            unsigned h0, h1, h2, h3, h5, h6, h7, h8;
            if constexpr (!ODD) {
                uint2 va = st64[b0 + 0], vb = st64[b0 + 1],
                      vc = st64[b0 + 2], vd = st64[b0 + 3];
                unsigned w8 = st32[2 * b0 + 8];
                h0 = va.x; h1 = va.y; h2 = vb.x; h3 = vb.y;
                h5 = vc.y; h6 = vd.x; h7 = vd.y; h8 = w8;
            } else {
                unsigned w0 = st32[2 * b0 + 1];
                uint2 va = st64[b0 + 1], vb = st64[b0 + 2],
                      vc = st64[b0 + 3], vd = st64[b0 + 4];
                h0 = w0;   h1 = va.x; h2 = va.y; h3 = vb.x;
                h5 = vc.x; h6 = vc.y; h7 = vd.x; h8 = vd.y;
            }
            __half2 N = *reinterpret_cast<__half2*>(&h5);
            __half  nh = __low2half(N);
            float   ns = __half2float(__high2half(N));
            float c2 = 1.0f - ns, c1 = ns - c2;
            #define EDGE_(hw) ({ __half2 _t = *reinterpret_cast<__half2*>(&(hw)); \
                (__hle(__habs(__hsub(__low2half(_t), nh)), Th)) \
                    ? fmaf(__half2float(__high2half(_t)), c1, c2) : 1.0f; })
            float f0 = EDGE_(h0);
            float f1 = EDGE_(h1);
            float f2 = EDGE_(h2);
            float f3 = EDGE_(h3);
            float f4 = fmaf(ns, c1, c2);       // self-edge q=5, |d|=0
            float f5 = EDGE_(h6);
            float f6 = EDGE_(h7);
            float f7 = EDGE_(h8);
            #undef EDGE_
            p = ((f0 * f1) * (f2 * f3)) * ((f4 * f5) * (f6 * f7));
        } else if (r0 + rowk < 1023) {
            // ---- row-wrap path: taps q>=qs from the LDS strip ----
            int a0 = (rowk + 2 + di) * SW_ + (colk + 4 + dj);
            int qs = 1024 - col0;                               // 1..8
            int sbase = SOFF + (rowk + 2 + di) * 12 + (col0 - 1022 + dj);
            #define RDW_(q) __half22float2(st[(((q) < qs) ? a0 : sbase) + (q)])
            float2 t0 = RDW_(0);
            float2 t1 = RDW_(1);
            float2 t2 = RDW_(2);
            float2 t3 = RDW_(3);
            float2 t5 = RDW_(5);
            float2 t6 = RDW_(6);
            float2 t7 = RDW_(7);
            float2 t8 = RDW_(8);
            #undef RDW_
            float nimg = t5.x;
            float c1 = 2.0f * t5.y - 1.0f, c2 = 1.0f - t5.y;
            float f0 = (fabsf(nimg - t0.x) <= T) ? fmaf(t0.y, c1, c2) : 1.0f;
            float f1 = (fabsf(nimg - t1.x) <= T) ? fmaf(t1.y, c1, c2) : 1.0f;
            float f2 = (fabsf(nimg - t2.x) <= T) ? fmaf(t2.y, c1, c2) : 1.0f;
            float f3 = (fabsf(nimg - t3.x) <= T) ? fmaf(t3.y, c1, c2) : 1.0f;
            float f4 = fmaf(t5.y, c1, c2);
            float f5 = (fabsf(nimg - t6.x) <= T) ? fmaf(t6.y, c1, c2) : 1.0f;
            float f6 = (fabsf(nimg - t7.x) <= T) ? fmaf(t7.y, c1, c2) : 1.0f;
            float f7 = (fabsf(nimg - t8.x) <= T) ? fmaf(t8.y, c1, c2) : 1.0f;
            p = ((f0 * f1) * (f2 * f3)) * ((f4 * f5) * (f6 * f7));
        } else {
            // ---- pi-crossing sites (si0 >= 2^20-8): exact global path ----
            int m0 = (int)pi * HW_ + ((r0 + rowk) << 10) + col0;   // = 9l
            float nimg = 0.0f, nm = 0.0f;
            {
                int m = m0 + 5;
                int piq = m >> 20, siq = m & (HW_ - 1);
                int iq = (piq * 171) >> 9, jq = piq - 3 * iq;
                int rq = (siq >> 10) + 2 * iq - 2;
                int cq = (siq & 1023) + 2 * jq - 2;
                if ((unsigned)rq < 1024u && (unsigned)cq < 1024u) {
                    int off = (rq << 10) | cq;
                    nimg = img[off];
                    nm = 1.0f / (1.0f + __expf(-lg[off]));
                }
            }
            float c1 = 2.0f * nm - 1.0f, c2 = 1.0f - nm;
            p = 1.0f;
            #pragma unroll
            for (int q = 0; q < 9; ++q) {
                if (q == 4) continue;
                int m = m0 + q;
                int piq = m >> 20, siq = m & (HW_ - 1);
                int iq = (piq * 171) >> 9, jq = piq - 3 * iq;
                int rq = (siq >> 10) + 2 * iq - 2;
                int cq = (siq & 1023) + 2 * jq - 2;
                float eimg = 0.0f, em = 0.0f;
                if ((unsigned)rq < 1024u && (unsigned)cq < 1024u) {
                    int off = (rq << 10) | cq;
                    eimg = img[off];
                    em = 1.0f / (1.0f + __expf(-lg[off]));
                }
                p *= (fabsf(nimg - eimg) <= T) ? fmaf(em, c1, c2) : 1.0f;
            }
        }
        if (u & 1) acc -= __log2f(pp * p);     // one log per row-pair (16 factors)
        else       pp = p;
        pi += 5u;                              // +2*1024 mod 9
        if (pi >= 9u) pi -= 9u;
    }
    return acc;
}

__global__ __launch_bounds__(NB_) void ploss18(
        const float* __restrict__ logits_,
        const float* __restrict__ image_,
        float* __restrict__ part, int nwg, float scale) {
    __shared__ __half2 st[SOFF + 144];   // 25.9 KB

    // bijective XCD-chunked swizzle (nwg % 8 == 0)
    int bid = blockIdx.x;
    int wg  = (bid & 7) * (nwg >> 3) + (bid >> 3);

    int c   = wg >> 8;                 // 256 blocks per class
    int rem = wg & 255;
    int r0  = (rem >> 1) * R_;
    int c0  = (rem & 1) * CW_;
    const float* __restrict__ img = image_  + (size_t)c * HW_;
    const float* __restrict__ lg  = logits_ + (size_t)c * HW_;
    int tid = threadIdx.x;

    // ---- stage PART A: staged rows 0..8 (strided; covers all 1188 groups) ----
    for (unsigned g = tid; g < NGA; g += NB_) {
        unsigned rr = g / 132u;            // 132 groups per row
        int gc  = (int)(g - rr * 132u);
        int row = r0 - 2 + (int)rr;
        int col4 = c0 - 4 + (gc << 2);
        float4 w;
        __half2* wh = reinterpret_cast<__half2*>(&w);
        if ((unsigned)row < 1024u && (unsigned)col4 < 1021u) {
            const float4 a = *reinterpret_cast<const float4*>(img + ((size_t)row << 10) + col4);
            const float4 b = *reinterpret_cast<const float4*>(lg  + ((size_t)row << 10) + col4);
            wh[0] = __floats2half2_rn(a.x, 1.0f / (1.0f + __expf(-b.x)));
            wh[1] = __floats2half2_rn(a.y, 1.0f / (1.0f + __expf(-b.y)));
            wh[2] = __floats2half2_rn(a.z, 1.0f / (1.0f + __expf(-b.z)));
            wh[3] = __floats2half2_rn(a.w, 1.0f / (1.0f + __expf(-b.w)));
        } else {
            w = make_float4(0.0f, 0.0f, 0.0f, 0.0f);
        }
        reinterpret_cast<float4*>(st)[g] = w;
    }
    // ---- strip (right tiles only): 12 rows [r0-1, r0+10], cols [-2, 10) ----
    if (c0 != 0 && tid < 144) {
        unsigned rr = (unsigned)tid / 12u;
        int cc = tid - (int)rr * 12;
        int row = r0 - 1 + (int)rr, col = cc - 2;
        float iv = 0.0f, mv = 0.0f;
        if ((unsigned)row < 1024u && (unsigned)col < 1024u) {
            int off = (row << 10) | col;
            iv = img[off];
            mv = 1.0f / (1.0f + __expf(-lg[off]));
        }
        st[SOFF + tid] = __floats2half2_rn(iv, mv);
    }
    // ---- PART B (staged rows 9..11, 396 groups): ISSUE loads to registers ----
    float4 bimg = make_float4(0.f,0.f,0.f,0.f), blg = make_float4(0.f,0.f,0.f,0.f);
    bool bok = false;
    if (tid < NGB) {
        unsigned gb = (unsigned)(NGA + tid);
        unsigned rr = gb / 132u;           // 9..11
        int gc  = (int)(gb - rr * 132u);
        int row = r0 - 2 + (int)rr;        // r0+7 .. r0+9
        int col4 = c0 - 4 + (gc << 2);
        bok = (unsigned)row < 1024u && (unsigned)col4 < 1021u;
        if (bok) {
            bimg = *reinterpret_cast<const float4*>(img + ((size_t)row << 10) + col4);
            blg  = *reinterpret_cast<const float4*>(lg  + ((size_t)row << 10) + col4);
        }
    }
    __syncthreads();                       // A + strip visible; B loads in flight

    // thread->site remap: waves 0-3 even cols, waves 4-7 odd cols (uniform parity)
    int tsub  = tid & 255;
    int colk0 = (tsub << 1) | (tid >> 8);
    int col0  = c0 + colk0;                // loop-invariant per thread
    unsigned pi0 = (2u * (unsigned)((r0 << 10) + col0)) % 9u;

    // ---- body half A: rows 0..3 (reads staged rows <= 7, subset of part A) ----
    float accA;
    if (tid < 256) accA = ploss_half<0,0>(st, img, lg, r0, col0, colk0, pi0);
    else           accA = ploss_half<1,0>(st, img, lg, r0, col0, colk0, pi0);

    // ---- write PART B (sigmoid + pack); rows 9..11 disjoint from body-A reads ----
    if (tid < NGB) {
        float4 w;
        __half2* wh = reinterpret_cast<__half2*>(&w);
        if (bok) {
            wh[0] = __floats2half2_rn(bimg.x, 1.0f / (1.0f + __expf(-blg.x)));
            wh[1] = __floats2half2_rn(bimg.y, 1.0f / (1.0f + __expf(-blg.y)));
            wh[2] = __floats2half2_rn(bimg.z, 1.0f / (1.0f + __expf(-blg.z)));
            wh[3] = __floats2half2_rn(bimg.w, 1.0f / (1.0f + __expf(-blg.w)));
        } else {
            w = make_float4(0.0f, 0.0f, 0.0f, 0.0f);
        }
        reinterpret_cast<float4*>(st)[NGA + tid] = w;
    }
    __syncthreads();                       // B visible

    // ---- body half B: rows 4..7 (reads staged rows 4..11) ----
    unsigned piB = pi0 + 2u; if (piB >= 9u) piB -= 9u;   // +4*5 mod 9
    float accB;
    if (tid < 256) accB = ploss_half<0,4>(st, img, lg, r0, col0, colk0, piB);
    else           accB = ploss_half<1,4>(st, img, lg, r0, col0, colk0, piB);

    float acc = (accA + accB) * scale;     // scale includes ln2

    // wave shuffle reduce -> LDS -> ONE plain store per block (no atomics)
    #pragma unroll
    for (int o = 32; o > 0; o >>= 1) acc += __shfl_down(acc, o, 64);
    __shared__ float sm[8];
    int lane = tid & 63, wid = tid >> 6;
    if (lane == 0) sm[wid] = acc;
    __syncthreads();
    if (tid == 0) {
        float s = 0.0f;
        #pragma unroll
        for (int w2 = 0; w2 < 8; ++w2) s += sm[w2];
        part[wg] = s;
    }
}

// single-block final reduce of nwg partials
__global__ __launch_bounds__(256) void preduce(
        const float* __restrict__ part, float* __restrict__ out, int n) {
    float acc = 0.0f;
    for (int i = threadIdx.x; i < n; i += 256) acc += part[i];
    #pragma unroll
    for (int o = 32; o > 0; o >>= 1) acc += __shfl_down(acc, o, 64);
    __shared__ float sm[4];
    int lane = threadIdx.x & 63, wid = threadIdx.x >> 6;
    if (lane == 0) sm[wid] = acc;
    __syncthreads();
    if (threadIdx.x == 0) out[0] = sm[0] + sm[1] + sm[2] + sm[3];
}

extern "C" void kernel_launch(void* const* d_in, const int* in_sizes, int n_in,
                              void* d_out, int out_size, void* d_ws, size_t ws_size,
                              hipStream_t stream) {
    const float* logits = (const float*)d_in[0];  // inputs (N,1,H,W) fp32
    const float* image  = (const float*)d_in[1];  // image  (N,1,H,W) fp32
    float* out  = (float*)d_out;
    float* part = (float*)d_ws;                   // nwg floats of scratch

    int nc  = in_sizes[0] / HW_;                          // 4
    int nwg = nc * (1024 / R_) * (1024 / CW_);            // 1024
    // acc is in log2 units -> fold ln2 into the scale
    float scale = 0.69314718055994531f / ((float)nc * (float)HW_);

    ploss18<<<nwg, NB_, 0, stream>>>(logits, image, part, nwg, scale);
    preduce<<<1, 256, 0, stream>>>(part, out, nwg);
}

// Round 19
// 23.564 us; speedup vs baseline: 1.4394x; 1.0157x over previous
//
#include <hip/hip_runtime.h>
#include <hip/hip_fp16.h>

#define HW_  (1024 * 1024)   // 2^20
#define R_   16              // output rows per block
#define RS_  (R_ + 4)        // staged rows [r0-2, r0+17]
#define CW_  512             // output cols per block
#define SW_  528             // staged cols [c0-4, c0+524), mult of 16 (bank-neutral di)
#define SOFF (RS_ * SW_)     // 10560 half2: strip starts here
#define NB_  512             // threads per block
#define NG   (SOFF / 4)      // 2640 float4 staging groups
#define NSTRIP (RS_ * 12)    // 240 strip entries

// Each si0 owns one output l: pi = (2*si0) mod 9, m0 = pi*2^20 + si0 = 9l.
// Taps q=0..8 at si0+q, node = tap q=5. WAVE-COUNT ROUND: R_=16 -> 512 blocks
// x 512 thr = 4096 waves (half of R12) to shrink dispatch/drain ramp.
// col0 loop-invariant per thread; wave-uniform parity; one log2 per row-pair.
template<int ODD>
__device__ __forceinline__ float ploss_body(
        const __half2* st, const float* __restrict__ img, const float* __restrict__ lg,
        int r0, int col0, int colk, unsigned pi) {
    const float  T  = 0.21072103131565256f;  // -2*ln(0.9)
    const __half Th = __float2half(0.21072103f);
    const uint2*    st64 = reinterpret_cast<const uint2*>(st);
    const unsigned* st32 = reinterpret_cast<const unsigned*>(st);
    float acc = 0.0f, pp = 1.0f;

    #pragma unroll
    for (int kk = 0; kk < R_; ++kk) {
        int rowk = kk;
        int i  = (int)((pi * 171u) >> 9);      // pi/3
        int j  = (int)pi - 3 * i;
        int di = 2 * i - 2, dj = 2 * j - 2;
        float p;
        if (col0 < 1016) {
            // ---- fast path: 4 b64 + 1 b32 LDS reads, parity-free extraction ----
            int b0 = ((rowk + 2 + di) * SW_ + (colk + 4 + dj)) >> 1;  // parity==ODD
            unsigned h0, h1, h2, h3, h5, h6, h7, h8;
            if constexpr (!ODD) {
                uint2 va = st64[b0 + 0], vb = st64[b0 + 1],
                      vc = st64[b0 + 2], vd = st64[b0 + 3];
                unsigned w8 = st32[2 * b0 + 8];
                h0 = va.x; h1 = va.y; h2 = vb.x; h3 = vb.y;
                h5 = vc.y; h6 = vd.x; h7 = vd.y; h8 = w8;
            } else {
                unsigned w0 = st32[2 * b0 + 1];
                uint2 va = st64[b0 + 1], vb = st64[b0 + 2],
                      vc = st64[b0 + 3], vd = st64[b0 + 4];
                h0 = w0;   h1 = va.x; h2 = va.y; h3 = vb.x;
                h5 = vc.x; h6 = vc.y; h7 = vd.x; h8 = vd.y;
            }
            __half2 N = *reinterpret_cast<__half2*>(&h5);
            __half  nh = __low2half(N);
            float   ns = __half2float(__high2half(N));
            float c2 = 1.0f - ns, c1 = ns - c2;
            #define EDGE_(hw) ({ __half2 _t = *reinterpret_cast<__half2*>(&(hw)); \
                (__hle(__habs(__hsub(__low2half(_t), nh)), Th)) \
                    ? fmaf(__half2float(__high2half(_t)), c1, c2) : 1.0f; })
            float f0 = EDGE_(h0);
            float f1 = EDGE_(h1);
            float f2 = EDGE_(h2);
            float f3 = EDGE_(h3);
            float f4 = fmaf(ns, c1, c2);       // self-edge q=5, |d|=0
            float f5 = EDGE_(h6);
            float f6 = EDGE_(h7);
            float f7 = EDGE_(h8);
            #undef EDGE_
            p = ((f0 * f1) * (f2 * f3)) * ((f4 * f5) * (f6 * f7));
        } else if (r0 + rowk < 1023) {
            // ---- row-wrap path: taps q>=qs from the LDS strip ----
            int a0 = (rowk + 2 + di) * SW_ + (colk + 4 + dj);
            int qs = 1024 - col0;                               // 1..8
            int sbase = SOFF + (rowk + 2 + di) * 12 + (col0 - 1022 + dj);
            #define RDW_(q) __half22float2(st[(((q) < qs) ? a0 : sbase) + (q)])
            float2 t0 = RDW_(0);
            float2 t1 = RDW_(1);
            float2 t2 = RDW_(2);
            float2 t3 = RDW_(3);
            float2 t5 = RDW_(5);
            float2 t6 = RDW_(6);
            float2 t7 = RDW_(7);
            float2 t8 = RDW_(8);
            #undef RDW_
            float nimg = t5.x;
            float c1 = 2.0f * t5.y - 1.0f, c2 = 1.0f - t5.y;
            float f0 = (fabsf(nimg - t0.x) <= T) ? fmaf(t0.y, c1, c2) : 1.0f;
            float f1 = (fabsf(nimg - t1.x) <= T) ? fmaf(t1.y, c1, c2) : 1.0f;
            float f2 = (fabsf(nimg - t2.x) <= T) ? fmaf(t2.y, c1, c2) : 1.0f;
            float f3 = (fabsf(nimg - t3.x) <= T) ? fmaf(t3.y, c1, c2) : 1.0f;
            float f4 = fmaf(t5.y, c1, c2);
            float f5 = (fabsf(nimg - t6.x) <= T) ? fmaf(t6.y, c1, c2) : 1.0f;
            float f6 = (fabsf(nimg - t7.x) <= T) ? fmaf(t7.y, c1, c2) : 1.0f;
            float f7 = (fabsf(nimg - t8.x) <= T) ? fmaf(t8.y, c1, c2) : 1.0f;
            p = ((f0 * f1) * (f2 * f3)) * ((f4 * f5) * (f6 * f7));
        } else {
            // ---- pi-crossing sites (si0 >= 2^20-8): exact global path ----
            int m0 = (int)pi * HW_ + ((r0 + rowk) << 10) + col0;   // = 9l
            float nimg = 0.0f, nm = 0.0f;
            {
                int m = m0 + 5;
                int piq = m >> 20, siq = m & (HW_ - 1);
                int iq = (piq * 171) >> 9, jq = piq - 3 * iq;
                int rq = (siq >> 10) + 2 * iq - 2;
                int cq = (siq & 1023) + 2 * jq - 2;
                if ((unsigned)rq < 1024u && (unsigned)cq < 1024u) {
                    int off = (rq << 10) | cq;
                    nimg = img[off];
                    nm = 1.0f / (1.0f + __expf(-lg[off]));
                }
            }
            float c1 = 2.0f * nm - 1.0f, c2 = 1.0f - nm;
            p = 1.0f;
            #pragma unroll
            for (int q = 0; q < 9; ++q) {
                if (q == 4) continue;
                int m = m0 + q;
                int piq = m >> 20, siq = m & (HW_ - 1);
                int iq = (piq * 171) >> 9, jq = piq - 3 * iq;
                int rq = (siq >> 10) + 2 * iq - 2;
                int cq = (siq & 1023) + 2 * jq - 2;
                float eimg = 0.0f, em = 0.0f;
                if ((unsigned)rq < 1024u && (unsigned)cq < 1024u) {
                    int off = (rq << 10) | cq;
                    eimg = img[off];
                    em = 1.0f / (1.0f + __expf(-lg[off]));
                }
                p *= (fabsf(nimg - eimg) <= T) ? fmaf(em, c1, c2) : 1.0f;
            }
        }
        if (kk & 1) acc -= __log2f(pp * p);    // one log per row-pair (16 factors)
        else        pp = p;
        pi += 5u;                              // +2*1024 mod 9
        if (pi >= 9u) pi -= 9u;
    }
    return acc;
}

__global__ __launch_bounds__(NB_) void ploss19(
        const float* __restrict__ logits_,
        const float* __restrict__ image_,
        float* __restrict__ part, int nwg, float scale) {
    __shared__ __half2 st[SOFF + NSTRIP];   // 43.2 KB

    // bijective XCD-chunked swizzle (nwg % 8 == 0)
    int bid = blockIdx.x;
    int wg  = (bid & 7) * (nwg >> 3) + (bid >> 3);

    int c   = wg >> 7;                 // 128 blocks per class
    int rem = wg & 127;
    int r0  = (rem >> 1) * R_;
    int c0  = (rem & 1) * CW_;
    const float* __restrict__ img = image_  + (size_t)c * HW_;
    const float* __restrict__ lg  = logits_ + (size_t)c * HW_;
    int tid = threadIdx.x;

    // ---- stage main tile: float4 groups, no partial vectors by construction ----
    for (unsigned g = tid; g < NG; g += NB_) {
        unsigned rr = g / 132u;            // 132 groups per row
        int gc  = (int)(g - rr * 132u);
        int row = r0 - 2 + (int)rr;
        int col4 = c0 - 4 + (gc << 2);
        float4 w;
        __half2* wh = reinterpret_cast<__half2*>(&w);
        if ((unsigned)row < 1024u && (unsigned)col4 < 1021u) {
            const float4 a = *reinterpret_cast<const float4*>(img + ((size_t)row << 10) + col4);
            const float4 b = *reinterpret_cast<const float4*>(lg  + ((size_t)row << 10) + col4);
            wh[0] = __floats2half2_rn(a.x, 1.0f / (1.0f + __expf(-b.x)));
            wh[1] = __floats2half2_rn(a.y, 1.0f / (1.0f + __expf(-b.y)));
            wh[2] = __floats2half2_rn(a.z, 1.0f / (1.0f + __expf(-b.z)));
            wh[3] = __floats2half2_rn(a.w, 1.0f / (1.0f + __expf(-b.w)));
        } else {
            w = make_float4(0.0f, 0.0f, 0.0f, 0.0f);
        }
        reinterpret_cast<float4*>(st)[g] = w;
    }
    // ---- strip (right tiles only): RS_ rows [r0-1, r0+18], cols [-2, 10) ----
    if (c0 != 0 && tid < NSTRIP) {
        unsigned rr = (unsigned)tid / 12u;
        int cc = tid - (int)rr * 12;
        int row = r0 - 1 + (int)rr, col = cc - 2;
        float iv = 0.0f, mv = 0.0f;
        if ((unsigned)row < 1024u && (unsigned)col < 1024u) {
            int off = (row << 10) | col;
            iv = img[off];
            mv = 1.0f / (1.0f + __expf(-lg[off]));
        }
        st[SOFF + tid] = __floats2half2_rn(iv, mv);
    }
    __syncthreads();

    // thread->site remap: waves 0-3 even cols, waves 4-7 odd cols (uniform parity)
    int tsub  = tid & 255;
    int colk0 = (tsub << 1) | (tid >> 8);
    int col0  = c0 + colk0;                    // loop-invariant per thread
    unsigned pi0 = (2u * (unsigned)((r0 << 10) + col0)) % 9u;

    float acc;
    if (tid < 256) acc = ploss_body<0>(st, img, lg, r0, col0, colk0, pi0);
    else           acc = ploss_body<1>(st, img, lg, r0, col0, colk0, pi0);
    acc *= scale;                              // scale includes ln2

    // wave shuffle reduce -> LDS -> ONE plain store per block (no atomics)
    #pragma unroll
    for (int o = 32; o > 0; o >>= 1) acc += __shfl_down(acc, o, 64);
    __shared__ float sm[8];
    int lane = tid & 63, wid = tid >> 6;
    if (lane == 0) sm[wid] = acc;
    __syncthreads();
    if (tid == 0) {
        float s = 0.0f;
        #pragma unroll
        for (int w2 = 0; w2 < 8; ++w2) s += sm[w2];
        part[wg] = s;
    }
}

// single-block final reduce of nwg partials
__global__ __launch_bounds__(256) void preduce(
        const float* __restrict__ part, float* __restrict__ out, int n) {
    float acc = 0.0f;
    for (int i = threadIdx.x; i < n; i += 256) acc += part[i];
    #pragma unroll
    for (int o = 32; o > 0; o >>= 1) acc += __shfl_down(acc, o, 64);
    __shared__ float sm[4];
    int lane = threadIdx.x & 63, wid = threadIdx.x >> 6;
    if (lane == 0) sm[wid] = acc;
    __syncthreads();
    if (threadIdx.x == 0) out[0] = sm[0] + sm[1] + sm[2] + sm[3];
}

extern "C" void kernel_launch(void* const* d_in, const int* in_sizes, int n_in,
                              void* d_out, int out_size, void* d_ws, size_t ws_size,
                              hipStream_t stream) {
    const float* logits = (const float*)d_in[0];  // inputs (N,1,H,W) fp32
    const float* image  = (const float*)d_in[1];  // image  (N,1,H,W) fp32
    float* out  = (float*)d_out;
    float* part = (float*)d_ws;                   // nwg floats of scratch

    int nc  = in_sizes[0] / HW_;                          // 4
    int nwg = nc * (1024 / R_) * (1024 / CW_);            // 512
    // acc is in log2 units -> fold ln2 into the scale
    float scale = 0.69314718055994531f / ((float)nc * (float)HW_);

    ploss19<<<nwg, NB_, 0, stream>>>(logits, image, part, nwg, scale);
    preduce<<<1, 256, 0, stream>>>(part, out, nwg);
}